// Round 2
// baseline (233.152 us; speedup 1.0000x reference)
//
#include <hip/hip_runtime.h>

#define DIM 2048
#define NQ 11
#define NROT 88
#define BSZ 64
#define NT 8
#define NPC 4   // DEGREE+1

// gate j in [0,44) within a layer; wire w <-> state bit p = 10 - w
__device__ __forceinline__ void decode_gate(int j, int& type, int& pt, int& pcb) {
    if (j < 11) {                       // RY wires 0..10
        type = 0; pt = 10 - j; pcb = -1;
    } else if (j < 22) {                // CRX ctrl i, tgt (i+1)%11, i = 10..0
        int i = 21 - j;
        type = 1; pcb = 10 - i;
        int tw = (i + 1 == NQ) ? 0 : i + 1;
        pt = 10 - tw;
    } else if (j < 33) {                // RY wires 0..10
        type = 0; pt = 10 - (j - 22); pcb = -1;
    } else if (j == 33) {               // CRX ctrl 10, tgt 9
        type = 1; pcb = 0; pt = 1;
    } else {                            // CRX ctrl i, tgt (i-1)%11, i = 0..9
        int i = j - 34;
        type = 1; pcb = 10 - i;
        int tw = (i + 10) % NQ;
        pt = 10 - tw;
    }
}

// ---------------------------------------------------------------------------
// Setup: normalize base states, init working = base, acc = pc[0]*base
// ---------------------------------------------------------------------------
__global__ __launch_bounds__(256) void setup_kernel(
    const float* __restrict__ base, const float* __restrict__ pc,
    float2* __restrict__ working, float2* __restrict__ acc)
{
    int b = blockIdx.x;
    int tid = threadIdx.x;
    __shared__ float red[4];
    float ssum = 0.f;
    for (int i = tid; i < DIM; i += 256) {
        float v = base[b * DIM + i];
        ssum += v * v;
    }
    for (int off = 32; off > 0; off >>= 1) ssum += __shfl_down(ssum, off, 64);
    if ((tid & 63) == 0) red[tid >> 6] = ssum;
    __syncthreads();
    if (tid == 0) red[0] = red[0] + red[1] + red[2] + red[3];
    __syncthreads();
    float inv = rsqrtf(red[0]);
    float p0 = pc[0];
    for (int i = tid; i < DIM; i += 256) {
        float v = base[b * DIM + i] * inv;
        working[b * DIM + i] = make_float2(v, 0.f);
        acc[b * DIM + i] = make_float2(p0 * v, 0.f);
    }
}

// ---------------------------------------------------------------------------
// Evolve: register-resident state. Thread tid holds amplitudes tid*8+j.
//   bit p<=2 : register butterfly (no comm)
//   bit 3..8 : shfl_xor butterfly (no barrier)
//   bit 9,10 : LDS exchange (SoA layout, conflict-free), 2 barriers
// ---------------------------------------------------------------------------
__global__ __launch_bounds__(256) void evolve_kernel(
    const float2* __restrict__ working, const float* __restrict__ uparams,
    const float* __restrict__ lcu, float2* __restrict__ partial, int tpb)
{
    __shared__ float exr[DIM], exi[DIM];
    __shared__ float sc[NROT], ss[NROT];

    const int nchunks = NT / tpb;
    const int b = blockIdx.x / nchunks;
    const int chunk = blockIdx.x - b * nchunks;
    const int tid = threadIdx.x;

    float sr[8], sim[8], ar[8], ai[8];
#pragma unroll
    for (int j = 0; j < 8; ++j) { ar[j] = 0.f; ai[j] = 0.f; }

    for (int tt = 0; tt < tpb; ++tt) {
        const int t = chunk * tpb + tt;
        __syncthreads();   // previous iteration's table/exchange fully consumed
        if (tid < NROT) {
            float th = 0.5f * uparams[(b * NT + t) * NROT + tid];
            sc[tid] = cosf(th); ss[tid] = sinf(th);
        }
        const float4* wsrc = (const float4*)(working + (size_t)b * DIM);
#pragma unroll
        for (int jj = 0; jj < 4; ++jj) {
            float4 v = wsrc[tid * 4 + jj];
            sr[2*jj]   = v.x; sim[2*jj]   = v.y;
            sr[2*jj+1] = v.z; sim[2*jj+1] = v.w;
        }
        __syncthreads();   // trig table ready

        int idx = 0;
        for (int layer = 0; layer < 2; ++layer) {
#pragma unroll
            for (int jg = 0; jg < 44; ++jg) {
                int type, pt, pcb;
                decode_gate(jg, type, pt, pcb);
                const float c = sc[idx], s = ss[idx];
                ++idx;
                if (type == 0) {
                    // ---- RY ----
                    if (pt <= 2) {
#pragma unroll
                        for (int m = 0; m < 4; ++m) {
                            int jl = ((m >> pt) << (pt + 1)) | (m & ((1 << pt) - 1));
                            int jh = jl | (1 << pt);
                            float lr = sr[jl], hr = sr[jh];
                            float li = sim[jl], hi = sim[jh];
                            sr[jl]  = c*lr - s*hr;  sr[jh]  = s*lr + c*hr;
                            sim[jl] = c*li - s*hi;  sim[jh] = s*li + c*hi;
                        }
                    } else if (pt <= 8) {
                        const int mask = 1 << (pt - 3);
                        const float sg = ((tid >> (pt - 3)) & 1) ? s : -s;
#pragma unroll
                        for (int j = 0; j < 8; ++j) {
                            float orr = __shfl_xor(sr[j],  mask, 64);
                            float ori = __shfl_xor(sim[j], mask, 64);
                            sr[j]  = c*sr[j]  + sg*orr;
                            sim[j] = c*sim[j] + sg*ori;
                        }
                    } else {
                        const int ptid = tid ^ (1 << (pt - 3));
                        const float sg = ((tid >> (pt - 3)) & 1) ? s : -s;
#pragma unroll
                        for (int j = 0; j < 8; ++j) { exr[j*256+tid] = sr[j]; exi[j*256+tid] = sim[j]; }
                        __syncthreads();
#pragma unroll
                        for (int j = 0; j < 8; ++j) {
                            float orr = exr[j*256+ptid];
                            float ori = exi[j*256+ptid];
                            sr[j]  = c*sr[j]  + sg*orr;
                            sim[j] = c*sim[j] + sg*ori;
                        }
                        __syncthreads();
                    }
                } else {
                    // ---- CRX (apply RX where control bit of amplitude == 1) ----
                    if (pt <= 2) {
#pragma unroll
                        for (int m = 0; m < 4; ++m) {
                            int jl = ((m >> pt) << (pt + 1)) | (m & ((1 << pt) - 1));
                            int jh = jl | (1 << pt);
                            int ctrl = (((tid << 3) | jl) >> pcb) & 1;
                            if (ctrl) {
                                float lr = sr[jl], li = sim[jl];
                                float hr = sr[jh], hi = sim[jh];
                                sr[jl]  = c*lr + s*hi;   sim[jl] = c*li - s*hr;
                                sr[jh]  = c*hr + s*li;   sim[jh] = c*hi - s*lr;
                            }
                        }
                    } else if (pt <= 8) {
                        const int mask = 1 << (pt - 3);
#pragma unroll
                        for (int j = 0; j < 8; ++j) {
                            float orr = __shfl_xor(sr[j],  mask, 64);
                            float ori = __shfl_xor(sim[j], mask, 64);
                            int ctrl = (((tid << 3) | j) >> pcb) & 1;
                            if (ctrl) {
                                float nr = c*sr[j]  + s*ori;
                                float ni = c*sim[j] - s*orr;
                                sr[j] = nr; sim[j] = ni;
                            }
                        }
                    } else {
                        const int ptid = tid ^ (1 << (pt - 3));
#pragma unroll
                        for (int j = 0; j < 8; ++j) { exr[j*256+tid] = sr[j]; exi[j*256+tid] = sim[j]; }
                        __syncthreads();
#pragma unroll
                        for (int j = 0; j < 8; ++j) {
                            float orr = exr[j*256+ptid];
                            float ori = exi[j*256+ptid];
                            int ctrl = (((tid << 3) | j) >> pcb) & 1;
                            if (ctrl) {
                                float nr = c*sr[j]  + s*ori;
                                float ni = c*sim[j] - s*orr;
                                sr[j] = nr; sim[j] = ni;
                            }
                        }
                        __syncthreads();
                    }
                }
            }
        }

        const float coeff = lcu[b * NT + t];
#pragma unroll
        for (int j = 0; j < 8; ++j) { ar[j] += coeff * sr[j]; ai[j] += coeff * sim[j]; }
    }

    float4* pdst = (float4*)(partial + ((size_t)b * nchunks + chunk) * DIM);
#pragma unroll
    for (int jj = 0; jj < 4; ++jj) {
        float4 v;
        v.x = ar[2*jj];   v.y = ai[2*jj];
        v.z = ar[2*jj+1]; v.w = ai[2*jj+1];
        pdst[tid * 4 + jj] = v;
    }
}

// ---------------------------------------------------------------------------
// Reduce: working[b] = sum_chunk partial; acc += pc[k]*working; maybe out
// grid = BSZ*8 blocks, one complex element per thread
// ---------------------------------------------------------------------------
__global__ __launch_bounds__(256) void reduce_kernel(
    const float2* __restrict__ partial, const float* __restrict__ pcoef,
    float2* __restrict__ working, float2* __restrict__ acc,
    float* __restrict__ out, int nchunks, int k, int last)
{
    int b = blockIdx.x >> 3;
    int i = ((blockIdx.x & 7) << 8) | threadIdx.x;
    float pk = pcoef[k];
    float sr = 0.f, si = 0.f;
    for (int c = 0; c < nchunks; ++c) {
        float2 v = partial[((size_t)b * nchunks + c) * DIM + i];
        sr += v.x; si += v.y;
    }
    working[b * DIM + i] = make_float2(sr, si);
    float2 a = acc[b * DIM + i];
    a.x += pk * sr; a.y += pk * si;
    acc[b * DIM + i] = a;
    if (last) {
        float sabs = 0.f;
        for (int q = 0; q < NPC; ++q) sabs += fabsf(pcoef[q]);
        float invn = 1.0f / sabs;
        out[((size_t)b * DIM + i) * 2 + 0] = a.x * invn;
        out[((size_t)b * DIM + i) * 2 + 1] = a.y * invn;
    }
}

extern "C" void kernel_launch(void* const* d_in, const int* in_sizes, int n_in,
                              void* d_out, int out_size, void* d_ws, size_t ws_size,
                              hipStream_t stream) {
    const float* base = (const float*)d_in[0];   // (64, 2048) f32
    const float* upar = (const float*)d_in[1];   // (64, 8, 88) f32
    const float* lcu  = (const float*)d_in[2];   // (64, 8) f32
    const float* pc   = (const float*)d_in[3];   // (4,) f32
    float* out = (float*)d_out;                  // (64, 2048, 2) f32

    const size_t plane = (size_t)BSZ * DIM * sizeof(float2);   // 1 MB
    char* ws = (char*)d_ws;
    float2* working = (float2*)ws;
    float2* acc     = (float2*)(ws + plane);
    float2* partial = (float2*)(ws + 2 * plane);

    int tpb = 1;
    while (tpb < NT && 2 * plane + (size_t)(NT / tpb) * plane > ws_size) tpb <<= 1;
    int nchunks = NT / tpb;

    setup_kernel<<<BSZ, 256, 0, stream>>>(base, pc, working, acc);
    for (int k = 1; k <= NPC - 1; ++k) {
        evolve_kernel<<<BSZ * nchunks, 256, 0, stream>>>(working, upar, lcu, partial, tpb);
        reduce_kernel<<<BSZ * 8, 256, 0, stream>>>(partial, pc, working, acc, out,
                                                   nchunks, k, (k == NPC - 1) ? 1 : 0);
    }
}

// Round 3
// 102.132 us; speedup vs baseline: 2.2828x; 2.2828x over previous
//
#include <hip/hip_runtime.h>
#include <utility>

#define DIM 2048
#define NQ 11
#define NROT 88
#define BSZ 64
#define NT 8
#define NPC 4   // DEGREE+1

// ---------------------------------------------------------------------------
// Compile-time gate schedule. Gate G in [0,88); wire w <-> state bit 10-w.
// ---------------------------------------------------------------------------
constexpr int g_type(int G) {
    int j = G % 44;
    return (j < 11 || (j >= 22 && j < 33)) ? 0 : 1;   // 0=RY, 1=CRX
}
constexpr int g_pt(int G) {
    int j = G % 44;
    if (j < 11) return 10 - j;
    if (j < 22) { int i = 21 - j; int tw = (i + 1 == NQ) ? 0 : i + 1; return 10 - tw; }
    if (j < 33) return 10 - (j - 22);
    if (j == 33) return 1;
    int i = j - 34; int tw = (i + 10) % NQ; return 10 - tw;
}
constexpr int g_pcb(int G) {
    int j = G % 44;
    if (j >= 11 && j < 22) { int i = 21 - j; return 10 - i; }
    if (j == 33) return 0;
    if (j >= 34) { int i = j - 34; return 10 - i; }
    return 0;  // unused for RY
}

// ---------------------------------------------------------------------------
// Static lane exchange: partner value across lane bit LB (state bit LB+3).
//  LB 0,1 : DPP quad_perm (VALU pipe)
//  LB 2..4: ds_swizzle immediate (LDS pipe, 1 instr, wave-sync)
//  LB 5   : shfl_xor 32 (ds_bpermute)
// ---------------------------------------------------------------------------
template<int LB>
__device__ __forceinline__ float lane_xor(float x) {
    if constexpr (LB == 0) {
        return __int_as_float(__builtin_amdgcn_update_dpp(
            __float_as_int(x), __float_as_int(x), 0xB1, 0xF, 0xF, true)); // quad_perm [1,0,3,2]
    } else if constexpr (LB == 1) {
        return __int_as_float(__builtin_amdgcn_update_dpp(
            __float_as_int(x), __float_as_int(x), 0x4E, 0xF, 0xF, true)); // quad_perm [2,3,0,1]
    } else if constexpr (LB == 2) {
        return __int_as_float(__builtin_amdgcn_ds_swizzle(__float_as_int(x), 0x101F)); // xor4
    } else if constexpr (LB == 3) {
        return __int_as_float(__builtin_amdgcn_ds_swizzle(__float_as_int(x), 0x201F)); // xor8
    } else if constexpr (LB == 4) {
        return __int_as_float(__builtin_amdgcn_ds_swizzle(__float_as_int(x), 0x401F)); // xor16
    } else {
        return __shfl_xor(x, 32, 64);                                                  // xor32
    }
}

// ---------------------------------------------------------------------------
// Apply gate G. Thread tid holds amplitudes a = tid*8 + j (j = 0..7).
// Local bits {0,1,2}; lane bits {3..8}; block bits {9,10}.
// ---------------------------------------------------------------------------
template<int G>
__device__ __forceinline__ void apply_gate(
    float (&sr)[8], float (&si)[8],
    const float* __restrict__ sc, const float* __restrict__ ss,
    float* __restrict__ exr, float* __restrict__ exi, const int tid)
{
    constexpr int type = g_type(G);
    constexpr int pt   = g_pt(G);
    constexpr int pcb  = g_pcb(G);
    const float c = sc[G];
    const float s = ss[G];

    if constexpr (pt <= 2) {
        // ---------------- register-local butterfly ----------------
        if constexpr (type == 0) {
#pragma unroll
            for (int m = 0; m < 4; ++m) {
                int jl = ((m >> pt) << (pt + 1)) | (m & ((1 << pt) - 1));
                int jh = jl | (1 << pt);
                float lr = sr[jl], hr = sr[jh];
                float li = si[jl], hi = si[jh];
                sr[jl] = c*lr - s*hr;  sr[jh] = s*lr + c*hr;
                si[jl] = c*li - s*hi;  si[jh] = s*li + c*hi;
            }
        } else if constexpr (pcb <= 2) {
            // control bit static per pair
#pragma unroll
            for (int m = 0; m < 4; ++m) {
                int jl = ((m >> pt) << (pt + 1)) | (m & ((1 << pt) - 1));
                int jh = jl | (1 << pt);
                if ((jl >> pcb) & 1) {
                    float lr = sr[jl], li = si[jl];
                    float hr = sr[jh], hi = si[jh];
                    sr[jl] = c*lr + s*hi;   si[jl] = c*li - s*hr;
                    sr[jh] = c*hr + s*li;   si[jh] = c*hi - s*lr;
                }
            }
        } else {
            const bool ctrl = (tid >> (pcb - 3)) & 1;
            if (ctrl) {
#pragma unroll
                for (int m = 0; m < 4; ++m) {
                    int jl = ((m >> pt) << (pt + 1)) | (m & ((1 << pt) - 1));
                    int jh = jl | (1 << pt);
                    float lr = sr[jl], li = si[jl];
                    float hr = sr[jh], hi = si[jh];
                    sr[jl] = c*lr + s*hi;   si[jl] = c*li - s*hr;
                    sr[jh] = c*hr + s*li;   si[jh] = c*hi - s*lr;
                }
            }
        }
    } else if constexpr (pt <= 8) {
        // ---------------- lane exchange ----------------
        constexpr int lb = pt - 3;
        if constexpr (type == 0) {
            const float sg = ((tid >> lb) & 1) ? s : -s;
#pragma unroll
            for (int j = 0; j < 8; ++j) {
                float pr = lane_xor<lb>(sr[j]);
                float pi = lane_xor<lb>(si[j]);
                sr[j] = c*sr[j] + sg*pr;
                si[j] = c*si[j] + sg*pi;
            }
        } else if constexpr (pcb <= 2) {
            // static control per local amp: half the j's drop at compile time
#pragma unroll
            for (int j = 0; j < 8; ++j) {
                if ((j >> pcb) & 1) {
                    float pr = lane_xor<lb>(sr[j]);
                    float pi = lane_xor<lb>(si[j]);
                    float nr = c*sr[j] + s*pi;
                    float ni = c*si[j] - s*pr;
                    sr[j] = nr; si[j] = ni;
                }
            }
        } else {
            // control is a lane/block bit; partner shares it -> safe to branch
            const bool ctrl = (tid >> (pcb - 3)) & 1;
            if (ctrl) {
#pragma unroll
                for (int j = 0; j < 8; ++j) {
                    float pr = lane_xor<lb>(sr[j]);
                    float pi = lane_xor<lb>(si[j]);
                    float nr = c*sr[j] + s*pi;
                    float ni = c*si[j] - s*pr;
                    sr[j] = nr; si[j] = ni;
                }
            }
        }
    } else {
        // ---------------- block-bit exchange via LDS ----------------
        const int ptid = tid ^ (1 << (pt - 3));   // ^64 or ^128
#pragma unroll
        for (int j = 0; j < 8; ++j) { exr[j*256+tid] = sr[j]; exi[j*256+tid] = si[j]; }
        __syncthreads();
        if constexpr (type == 0) {
            const float sg = ((tid >> (pt - 3)) & 1) ? s : -s;
#pragma unroll
            for (int j = 0; j < 8; ++j) {
                float pr = exr[j*256+ptid], pi = exi[j*256+ptid];
                sr[j] = c*sr[j] + sg*pr;
                si[j] = c*si[j] + sg*pi;
            }
        } else if constexpr (pcb <= 2) {
#pragma unroll
            for (int j = 0; j < 8; ++j) {
                if ((j >> pcb) & 1) {
                    float pr = exr[j*256+ptid], pi = exi[j*256+ptid];
                    float nr = c*sr[j] + s*pi;
                    float ni = c*si[j] - s*pr;
                    sr[j] = nr; si[j] = ni;
                }
            }
        } else {
            const bool ctrl = (tid >> (pcb - 3)) & 1;
            if (ctrl) {
#pragma unroll
                for (int j = 0; j < 8; ++j) {
                    float pr = exr[j*256+ptid], pi = exi[j*256+ptid];
                    float nr = c*sr[j] + s*pi;
                    float ni = c*si[j] - s*pr;
                    sr[j] = nr; si[j] = ni;
                }
            }
        }
        __syncthreads();
    }
}

template<int... Gs>
__device__ __forceinline__ void apply_all(std::integer_sequence<int, Gs...>,
    float (&sr)[8], float (&si)[8],
    const float* __restrict__ sc, const float* __restrict__ ss,
    float* __restrict__ exr, float* __restrict__ exi, const int tid)
{
    (apply_gate<Gs>(sr, si, sc, ss, exr, exi, tid), ...);
}

// ---------------------------------------------------------------------------
// Setup: normalize base states, init working = base, acc = pc[0]*base
// ---------------------------------------------------------------------------
__global__ __launch_bounds__(256) void setup_kernel(
    const float* __restrict__ base, const float* __restrict__ pc,
    float2* __restrict__ working, float2* __restrict__ acc)
{
    int b = blockIdx.x;
    int tid = threadIdx.x;
    __shared__ float red[4];
    float ssum = 0.f;
    for (int i = tid; i < DIM; i += 256) {
        float v = base[b * DIM + i];
        ssum += v * v;
    }
    for (int off = 32; off > 0; off >>= 1) ssum += __shfl_down(ssum, off, 64);
    if ((tid & 63) == 0) red[tid >> 6] = ssum;
    __syncthreads();
    if (tid == 0) red[0] = red[0] + red[1] + red[2] + red[3];
    __syncthreads();
    float inv = rsqrtf(red[0]);
    float p0 = pc[0];
    for (int i = tid; i < DIM; i += 256) {
        float v = base[b * DIM + i] * inv;
        working[b * DIM + i] = make_float2(v, 0.f);
        acc[b * DIM + i] = make_float2(p0 * v, 0.f);
    }
}

// ---------------------------------------------------------------------------
// Evolve: fully static 88-gate straight-line body.
// ---------------------------------------------------------------------------
__global__ __launch_bounds__(256) void evolve_kernel(
    const float2* __restrict__ working, const float* __restrict__ uparams,
    const float* __restrict__ lcu, float2* __restrict__ partial, int tpb)
{
    __shared__ float exr[DIM], exi[DIM];
    __shared__ float sc[NROT], ss[NROT];

    const int nchunks = NT / tpb;
    const int b = blockIdx.x / nchunks;
    const int chunk = blockIdx.x - b * nchunks;
    const int tid = threadIdx.x;

    float sr[8], si[8], ar[8], ai[8];
#pragma unroll
    for (int j = 0; j < 8; ++j) { ar[j] = 0.f; ai[j] = 0.f; }

    for (int tt = 0; tt < tpb; ++tt) {
        const int t = chunk * tpb + tt;
        __syncthreads();   // prior iteration fully consumed sc/ss/exr/exi
        if (tid < NROT) {
            float th = 0.5f * uparams[(b * NT + t) * NROT + tid];
            sc[tid] = cosf(th); ss[tid] = sinf(th);
        }
        const float4* wsrc = (const float4*)(working + (size_t)b * DIM);
#pragma unroll
        for (int jj = 0; jj < 4; ++jj) {
            float4 v = wsrc[tid * 4 + jj];
            sr[2*jj]   = v.x; si[2*jj]   = v.y;
            sr[2*jj+1] = v.z; si[2*jj+1] = v.w;
        }
        __syncthreads();   // trig table ready

        apply_all(std::make_integer_sequence<int, NROT>{}, sr, si, sc, ss, exr, exi, tid);

        const float coeff = lcu[b * NT + t];
#pragma unroll
        for (int j = 0; j < 8; ++j) { ar[j] += coeff * sr[j]; ai[j] += coeff * si[j]; }
    }

    float4* pdst = (float4*)(partial + ((size_t)b * nchunks + chunk) * DIM);
#pragma unroll
    for (int jj = 0; jj < 4; ++jj) {
        float4 v;
        v.x = ar[2*jj];   v.y = ai[2*jj];
        v.z = ar[2*jj+1]; v.w = ai[2*jj+1];
        pdst[tid * 4 + jj] = v;
    }
}

// ---------------------------------------------------------------------------
// Reduce: working[b] = sum_chunk partial; acc += pc[k]*working; maybe out
// ---------------------------------------------------------------------------
__global__ __launch_bounds__(256) void reduce_kernel(
    const float2* __restrict__ partial, const float* __restrict__ pcoef,
    float2* __restrict__ working, float2* __restrict__ acc,
    float* __restrict__ out, int nchunks, int k, int last)
{
    int b = blockIdx.x >> 3;
    int i = ((blockIdx.x & 7) << 8) | threadIdx.x;
    float pk = pcoef[k];
    float sr = 0.f, si = 0.f;
    for (int c = 0; c < nchunks; ++c) {
        float2 v = partial[((size_t)b * nchunks + c) * DIM + i];
        sr += v.x; si += v.y;
    }
    working[b * DIM + i] = make_float2(sr, si);
    float2 a = acc[b * DIM + i];
    a.x += pk * sr; a.y += pk * si;
    acc[b * DIM + i] = a;
    if (last) {
        float sabs = 0.f;
        for (int q = 0; q < NPC; ++q) sabs += fabsf(pcoef[q]);
        float invn = 1.0f / sabs;
        out[((size_t)b * DIM + i) * 2 + 0] = a.x * invn;
        out[((size_t)b * DIM + i) * 2 + 1] = a.y * invn;
    }
}

extern "C" void kernel_launch(void* const* d_in, const int* in_sizes, int n_in,
                              void* d_out, int out_size, void* d_ws, size_t ws_size,
                              hipStream_t stream) {
    const float* base = (const float*)d_in[0];   // (64, 2048) f32
    const float* upar = (const float*)d_in[1];   // (64, 8, 88) f32
    const float* lcu  = (const float*)d_in[2];   // (64, 8) f32
    const float* pc   = (const float*)d_in[3];   // (4,) f32
    float* out = (float*)d_out;                  // (64, 2048, 2) f32

    const size_t plane = (size_t)BSZ * DIM * sizeof(float2);   // 1 MB
    char* ws = (char*)d_ws;
    float2* working = (float2*)ws;
    float2* acc     = (float2*)(ws + plane);
    float2* partial = (float2*)(ws + 2 * plane);

    int tpb = 1;
    while (tpb < NT && 2 * plane + (size_t)(NT / tpb) * plane > ws_size) tpb <<= 1;
    int nchunks = NT / tpb;

    setup_kernel<<<BSZ, 256, 0, stream>>>(base, pc, working, acc);
    for (int k = 1; k <= NPC - 1; ++k) {
        evolve_kernel<<<BSZ * nchunks, 256, 0, stream>>>(working, upar, lcu, partial, tpb);
        reduce_kernel<<<BSZ * 8, 256, 0, stream>>>(partial, pc, working, acc, out,
                                                   nchunks, k, (k == NPC - 1) ? 1 : 0);
    }
}

// Round 4
// 101.006 us; speedup vs baseline: 2.3083x; 1.0111x over previous
//
#include <hip/hip_runtime.h>
#include <utility>

#define DIM 2048
#define NQ 11
#define NROT 88
#define BSZ 64
#define NT 8
#define NPC 4   // DEGREE+1

// ---------------------------------------------------------------------------
// Compile-time gate schedule. Gate G in [0,88); wire w <-> state bit 10-w.
// ---------------------------------------------------------------------------
constexpr int g_type(int G) {
    int j = G % 44;
    return (j < 11 || (j >= 22 && j < 33)) ? 0 : 1;   // 0=RY, 1=CRX
}
constexpr int g_pt(int G) {
    int j = G % 44;
    if (j < 11) return 10 - j;
    if (j < 22) { int i = 21 - j; int tw = (i + 1 == NQ) ? 0 : i + 1; return 10 - tw; }
    if (j < 33) return 10 - (j - 22);
    if (j == 33) return 1;
    int i = j - 34; int tw = (i + 10) % NQ; return 10 - tw;
}
constexpr int g_pcb(int G) {
    int j = G % 44;
    if (j >= 11 && j < 22) { int i = 21 - j; return 10 - i; }
    if (j == 33) return 0;
    if (j >= 34) { int i = j - 34; return 10 - i; }
    return -1;  // RY
}
constexpr int block_parity(int G) {          // parity of #block-bit gates before G
    int c = 0;
    for (int g = 0; g < G; ++g) if (g_pt(g) >= 9) c ^= 1;
    return c;
}

// ---------------------------------------------------------------------------
// Lane exchange across state bit PT (lane bit PT-3).
//  PT 3,4 : DPP quad_perm (VALU pipe)
//  PT 5..7: ds_swizzle immediate
//  PT 8   : shfl_xor 32
// ---------------------------------------------------------------------------
template<int PT>
__device__ __forceinline__ float lx(float x) {
    if constexpr (PT == 3) {
        return __int_as_float(__builtin_amdgcn_update_dpp(
            __float_as_int(x), __float_as_int(x), 0xB1, 0xF, 0xF, true));
    } else if constexpr (PT == 4) {
        return __int_as_float(__builtin_amdgcn_update_dpp(
            __float_as_int(x), __float_as_int(x), 0x4E, 0xF, 0xF, true));
    } else if constexpr (PT == 5) {
        return __int_as_float(__builtin_amdgcn_ds_swizzle(__float_as_int(x), 0x101F));
    } else if constexpr (PT == 6) {
        return __int_as_float(__builtin_amdgcn_ds_swizzle(__float_as_int(x), 0x201F));
    } else if constexpr (PT == 7) {
        return __int_as_float(__builtin_amdgcn_ds_swizzle(__float_as_int(x), 0x401F));
    } else {
        return __shfl_xor(x, 32, 64);
    }
}

// ---------------------------------------------------------------------------
// State layout: thread tid holds amps a = tid*8 + j, j = 2m+e (m slot, e comp).
//   R[m] = (re(2m), re(2m+1)), I[m] = (im(2m), im(2m+1))
//   a bits: 0 = e, 1-2 = m, 3-8 = lane, 9-10 = wave index (tid bits 6,7)
// ---------------------------------------------------------------------------
template<int G>
__device__ __forceinline__ void apply_gate(
    float2 (&R)[4], float2 (&I)[4],
    const float* __restrict__ sc, const float* __restrict__ ss,
    float4* __restrict__ exbuf, const int tid)
{
    constexpr int type = g_type(G);
    constexpr int pt   = g_pt(G);
    constexpr int pcb  = g_pcb(G);
    const float c = sc[G];
    const float s = ss[G];

    if constexpr (pt == 0) {
        // -------- component pair (e bit) --------
        if constexpr (type == 0) {
#pragma unroll
            for (int m = 0; m < 4; ++m) {
                float er = R[m].x, orr = R[m].y, ei = I[m].x, oi = I[m].y;
                R[m].x = c*er - s*orr;  R[m].y = s*er + c*orr;
                I[m].x = c*ei - s*oi;   I[m].y = s*ei + c*oi;
            }
        } else if constexpr (pcb == 1 || pcb == 2) {
            constexpr int cb = pcb - 1;
#pragma unroll
            for (int m = 0; m < 4; ++m) {
                if ((m >> cb) & 1) {
                    float er = R[m].x, orr = R[m].y, ei = I[m].x, oi = I[m].y;
                    R[m].x = c*er + s*oi;   I[m].x = c*ei - s*orr;
                    R[m].y = c*orr + s*ei;  I[m].y = c*oi - s*er;
                }
            }
        } else {
            const bool ctrl = (tid >> (pcb - 3)) & 1;
            if (ctrl) {
#pragma unroll
                for (int m = 0; m < 4; ++m) {
                    float er = R[m].x, orr = R[m].y, ei = I[m].x, oi = I[m].y;
                    R[m].x = c*er + s*oi;   I[m].x = c*ei - s*orr;
                    R[m].y = c*orr + s*ei;  I[m].y = c*oi - s*er;
                }
            }
        }
    } else if constexpr (pt <= 2) {
        // -------- slot pair (m bit pt-1) --------
        constexpr int sb = pt - 1;
        if constexpr (type == 0) {
#pragma unroll
            for (int q = 0; q < 2; ++q) {
                constexpr int dummy = 0; (void)dummy;
                int ml = ((q >> sb) << (sb + 1)) | (q & ((1 << sb) - 1));
                int mh = ml | (1 << sb);
                float2 lr = R[ml], hr = R[mh], li = I[ml], hi = I[mh];
                R[ml].x = c*lr.x - s*hr.x;  R[ml].y = c*lr.y - s*hr.y;
                R[mh].x = s*lr.x + c*hr.x;  R[mh].y = s*lr.y + c*hr.y;
                I[ml].x = c*li.x - s*hi.x;  I[ml].y = c*li.y - s*hi.y;
                I[mh].x = s*li.x + c*hi.x;  I[mh].y = s*li.y + c*hi.y;
            }
        } else if constexpr (pcb == 0) {
            // ctrl = component: RX on odd components of each pair
#pragma unroll
            for (int q = 0; q < 2; ++q) {
                int ml = ((q >> sb) << (sb + 1)) | (q & ((1 << sb) - 1));
                int mh = ml | (1 << sb);
                float lr = R[ml].y, li = I[ml].y, hr = R[mh].y, hi = I[mh].y;
                R[ml].y = c*lr + s*hi;   I[ml].y = c*li - s*hr;
                R[mh].y = c*hr + s*li;   I[mh].y = c*hi - s*lr;
            }
        } else if constexpr (pcb == 1 || pcb == 2) {
            constexpr int cb = pcb - 1;
#pragma unroll
            for (int q = 0; q < 2; ++q) {
                int ml = ((q >> sb) << (sb + 1)) | (q & ((1 << sb) - 1));
                int mh = ml | (1 << sb);
                if ((ml >> cb) & 1) {
                    float2 lr = R[ml], li = I[ml], hr = R[mh], hi = I[mh];
                    R[ml].x = c*lr.x + s*hi.x;  R[ml].y = c*lr.y + s*hi.y;
                    I[ml].x = c*li.x - s*hr.x;  I[ml].y = c*li.y - s*hr.y;
                    R[mh].x = c*hr.x + s*li.x;  R[mh].y = c*hr.y + s*li.y;
                    I[mh].x = c*hi.x - s*lr.x;  I[mh].y = c*hi.y - s*lr.y;
                }
            }
        } else {
            const bool ctrl = (tid >> (pcb - 3)) & 1;
            if (ctrl) {
#pragma unroll
                for (int q = 0; q < 2; ++q) {
                    int ml = ((q >> sb) << (sb + 1)) | (q & ((1 << sb) - 1));
                    int mh = ml | (1 << sb);
                    float2 lr = R[ml], li = I[ml], hr = R[mh], hi = I[mh];
                    R[ml].x = c*lr.x + s*hi.x;  R[ml].y = c*lr.y + s*hi.y;
                    I[ml].x = c*li.x - s*hr.x;  I[ml].y = c*li.y - s*hr.y;
                    R[mh].x = c*hr.x + s*li.x;  R[mh].y = c*hr.y + s*li.y;
                    I[mh].x = c*hi.x - s*lr.x;  I[mh].y = c*hi.y - s*lr.y;
                }
            }
        }
    } else if constexpr (pt <= 8) {
        // -------- lane exchange --------
        if constexpr (type == 0) {
            const float sg = ((tid >> (pt - 3)) & 1) ? s : -s;
#pragma unroll
            for (int m = 0; m < 4; ++m) {
                float prx = lx<pt>(R[m].x), pry = lx<pt>(R[m].y);
                float pix = lx<pt>(I[m].x), piy = lx<pt>(I[m].y);
                R[m].x = c*R[m].x + sg*prx;  R[m].y = c*R[m].y + sg*pry;
                I[m].x = c*I[m].x + sg*pix;  I[m].y = c*I[m].y + sg*piy;
            }
        } else if constexpr (pcb == 0) {
            // only odd components participate -> exchange only those
#pragma unroll
            for (int m = 0; m < 4; ++m) {
                float pry = lx<pt>(R[m].y), piy = lx<pt>(I[m].y);
                R[m].y = c*R[m].y + s*piy;
                I[m].y = c*I[m].y - s*pry;
            }
        } else if constexpr (pcb == 1 || pcb == 2) {
            constexpr int cb = pcb - 1;
#pragma unroll
            for (int m = 0; m < 4; ++m) {
                if ((m >> cb) & 1) {
                    float prx = lx<pt>(R[m].x), pry = lx<pt>(R[m].y);
                    float pix = lx<pt>(I[m].x), piy = lx<pt>(I[m].y);
                    R[m].x = c*R[m].x + s*pix;  R[m].y = c*R[m].y + s*piy;
                    I[m].x = c*I[m].x - s*prx;  I[m].y = c*I[m].y - s*pry;
                }
            }
        } else {
            const bool ctrl = (tid >> (pcb - 3)) & 1;
            if (ctrl) {
#pragma unroll
                for (int m = 0; m < 4; ++m) {
                    float prx = lx<pt>(R[m].x), pry = lx<pt>(R[m].y);
                    float pix = lx<pt>(I[m].x), piy = lx<pt>(I[m].y);
                    R[m].x = c*R[m].x + s*pix;  R[m].y = c*R[m].y + s*piy;
                    I[m].x = c*I[m].x - s*prx;  I[m].y = c*I[m].y - s*pry;
                }
            }
        }
    } else {
        // -------- block-bit exchange via LDS (float4, dbuf, 1 barrier) --------
        constexpr int par = block_parity(G);
        float4* buf = exbuf + par * 1024;
        const int ptid = tid ^ (1 << (pt - 3));   // ^64 or ^128
        bool participate = true;
        if constexpr (type == 1 && pcb >= 3) participate = (tid >> (pcb - 3)) & 1;
        if (participate) {
#pragma unroll
            for (int m = 0; m < 4; ++m)
                buf[m * 256 + tid] = make_float4(R[m].x, R[m].y, I[m].x, I[m].y);
        }
        __syncthreads();
        if (participate) {
            if constexpr (type == 0) {
                const float sg = ((tid >> (pt - 3)) & 1) ? s : -s;
#pragma unroll
                for (int m = 0; m < 4; ++m) {
                    float4 v = buf[m * 256 + ptid];
                    R[m].x = c*R[m].x + sg*v.x;  R[m].y = c*R[m].y + sg*v.y;
                    I[m].x = c*I[m].x + sg*v.z;  I[m].y = c*I[m].y + sg*v.w;
                }
            } else if constexpr (pcb == 0) {
#pragma unroll
                for (int m = 0; m < 4; ++m) {
                    float4 v = buf[m * 256 + ptid];
                    R[m].y = c*R[m].y + s*v.w;
                    I[m].y = c*I[m].y - s*v.y;
                }
            } else if constexpr (pcb == 1 || pcb == 2) {
                constexpr int cb = pcb - 1;
#pragma unroll
                for (int m = 0; m < 4; ++m) {
                    if ((m >> cb) & 1) {
                        float4 v = buf[m * 256 + ptid];
                        R[m].x = c*R[m].x + s*v.z;  R[m].y = c*R[m].y + s*v.w;
                        I[m].x = c*I[m].x - s*v.x;  I[m].y = c*I[m].y - s*v.y;
                    }
                }
            } else {
#pragma unroll
                for (int m = 0; m < 4; ++m) {
                    float4 v = buf[m * 256 + ptid];
                    R[m].x = c*R[m].x + s*v.z;  R[m].y = c*R[m].y + s*v.w;
                    I[m].x = c*I[m].x - s*v.x;  I[m].y = c*I[m].y - s*v.y;
                }
            }
        }
        // no trailing barrier: this parity buffer is next written 2 exchanges
        // later; the intervening exchange's barrier orders reads before writes.
    }
}

template<int... Gs>
__device__ __forceinline__ void apply_all(std::integer_sequence<int, Gs...>,
    float2 (&R)[4], float2 (&I)[4],
    const float* __restrict__ sc, const float* __restrict__ ss,
    float4* __restrict__ exbuf, const int tid)
{
    (apply_gate<Gs>(R, I, sc, ss, exbuf, tid), ...);
}

// ---------------------------------------------------------------------------
// Setup: normalize base states, init working = base, acc = pc[0]*base
// ---------------------------------------------------------------------------
__global__ __launch_bounds__(256) void setup_kernel(
    const float* __restrict__ base, const float* __restrict__ pc,
    float2* __restrict__ working, float2* __restrict__ acc)
{
    int b = blockIdx.x;
    int tid = threadIdx.x;
    __shared__ float red[4];
    float ssum = 0.f;
    for (int i = tid; i < DIM; i += 256) {
        float v = base[b * DIM + i];
        ssum += v * v;
    }
    for (int off = 32; off > 0; off >>= 1) ssum += __shfl_down(ssum, off, 64);
    if ((tid & 63) == 0) red[tid >> 6] = ssum;
    __syncthreads();
    if (tid == 0) red[0] = red[0] + red[1] + red[2] + red[3];
    __syncthreads();
    float inv = rsqrtf(red[0]);
    float p0 = pc[0];
    for (int i = tid; i < DIM; i += 256) {
        float v = base[b * DIM + i] * inv;
        working[b * DIM + i] = make_float2(v, 0.f);
        acc[b * DIM + i] = make_float2(p0 * v, 0.f);
    }
}

// ---------------------------------------------------------------------------
// Evolve. FROM_PARTIAL: src is previous step's partials (b,chunk)-major;
// block inline-reduces them to the working vector; chunk-0 blocks also fold
// pc[kprev]*working into acc. Otherwise src = working (b-major).
// ---------------------------------------------------------------------------
template<bool FROM_PARTIAL>
__global__ __launch_bounds__(256) void evolve_kernel(
    const float2* __restrict__ src, const float* __restrict__ uparams,
    const float* __restrict__ lcu, float2* __restrict__ pout,
    const float* __restrict__ pcoef, float2* __restrict__ acc,
    int kprev, int tpb)
{
    __shared__ float4 exbuf[2048];          // 2 x 1024 float4 (dbuf)
    __shared__ float sc[NROT], ss[NROT];

    const int nchunks = NT / tpb;
    const int b = blockIdx.x / nchunks;
    const int chunk = blockIdx.x - b * nchunks;
    const int tid = threadIdx.x;

    float2 WR[4], WI[4];
    if constexpr (FROM_PARTIAL) {
#pragma unroll
        for (int m = 0; m < 4; ++m) { WR[m] = make_float2(0.f, 0.f); WI[m] = make_float2(0.f, 0.f); }
        for (int c = 0; c < NT; ++c) {
            const float4* p4 = (const float4*)(src + ((size_t)b * NT + c) * DIM);
#pragma unroll
            for (int m = 0; m < 4; ++m) {
                float4 v = p4[tid * 4 + m];
                WR[m].x += v.x; WI[m].x += v.y; WR[m].y += v.z; WI[m].y += v.w;
            }
        }
        if (kprev > 0 && chunk == 0) {
            float pk = pcoef[kprev];
            float4* a4 = (float4*)(acc + (size_t)b * DIM);
#pragma unroll
            for (int m = 0; m < 4; ++m) {
                float4 v = a4[tid * 4 + m];
                v.x += pk * WR[m].x; v.y += pk * WI[m].x;
                v.z += pk * WR[m].y; v.w += pk * WI[m].y;
                a4[tid * 4 + m] = v;
            }
        }
    } else {
        const float4* p4 = (const float4*)(src + (size_t)b * DIM);
#pragma unroll
        for (int m = 0; m < 4; ++m) {
            float4 v = p4[tid * 4 + m];
            WR[m].x = v.x; WI[m].x = v.y; WR[m].y = v.z; WI[m].y = v.w;
        }
    }

    float2 AR[4], AI[4];
#pragma unroll
    for (int m = 0; m < 4; ++m) { AR[m] = make_float2(0.f, 0.f); AI[m] = make_float2(0.f, 0.f); }

    for (int tt = 0; tt < tpb; ++tt) {
        const int t = chunk * tpb + tt;
        __syncthreads();                        // prior iter fully consumed LDS
        if (tid < NROT) {
            float th = 0.5f * uparams[(b * NT + t) * NROT + tid];
            sc[tid] = cosf(th); ss[tid] = sinf(th);
        }
        float2 R[4], I[4];
#pragma unroll
        for (int m = 0; m < 4; ++m) { R[m] = WR[m]; I[m] = WI[m]; }
        __syncthreads();                        // trig ready

        apply_all(std::make_integer_sequence<int, NROT>{}, R, I, sc, ss, exbuf, tid);

        const float coeff = lcu[b * NT + t];
#pragma unroll
        for (int m = 0; m < 4; ++m) {
            AR[m].x += coeff * R[m].x;  AR[m].y += coeff * R[m].y;
            AI[m].x += coeff * I[m].x;  AI[m].y += coeff * I[m].y;
        }
    }

    float4* o4 = (float4*)(pout + ((size_t)b * nchunks + chunk) * DIM);
#pragma unroll
    for (int m = 0; m < 4; ++m)
        o4[tid * 4 + m] = make_float4(AR[m].x, AI[m].x, AR[m].y, AI[m].y);
}

// ---------------------------------------------------------------------------
// Final: out = (acc + pc[NPC-1] * rowsum(partial_last)) / sum|pc|
// ---------------------------------------------------------------------------
__global__ __launch_bounds__(256) void final_kernel(
    const float2* __restrict__ partial, const float* __restrict__ pcoef,
    const float2* __restrict__ acc, float* __restrict__ out)
{
    int b = blockIdx.x >> 3;
    int i = ((blockIdx.x & 7) << 8) | threadIdx.x;
    float sr = 0.f, si = 0.f;
    for (int c = 0; c < NT; ++c) {
        float2 v = partial[((size_t)b * NT + c) * DIM + i];
        sr += v.x; si += v.y;
    }
    float sabs = 0.f;
    for (int q = 0; q < NPC; ++q) sabs += fabsf(pcoef[q]);
    float invn = 1.0f / sabs;
    float pk = pcoef[NPC - 1];
    float2 a = acc[(size_t)b * DIM + i];
    out[((size_t)b * DIM + i) * 2 + 0] = (a.x + pk * sr) * invn;
    out[((size_t)b * DIM + i) * 2 + 1] = (a.y + pk * si) * invn;
}

// ---------------------------------------------------------------------------
// Fallback reduce (small-ws path): working = rowsum(partial); acc += pc[k]*;
// ---------------------------------------------------------------------------
__global__ __launch_bounds__(256) void reduce_kernel(
    const float2* __restrict__ partial, const float* __restrict__ pcoef,
    float2* __restrict__ working, float2* __restrict__ acc,
    float* __restrict__ out, int nchunks, int k, int last)
{
    int b = blockIdx.x >> 3;
    int i = ((blockIdx.x & 7) << 8) | threadIdx.x;
    float pk = pcoef[k];
    float sr = 0.f, si = 0.f;
    for (int c = 0; c < nchunks; ++c) {
        float2 v = partial[((size_t)b * nchunks + c) * DIM + i];
        sr += v.x; si += v.y;
    }
    working[b * DIM + i] = make_float2(sr, si);
    float2 a = acc[b * DIM + i];
    a.x += pk * sr; a.y += pk * si;
    acc[b * DIM + i] = a;
    if (last) {
        float sabs = 0.f;
        for (int q = 0; q < NPC; ++q) sabs += fabsf(pcoef[q]);
        float invn = 1.0f / sabs;
        out[((size_t)b * DIM + i) * 2 + 0] = a.x * invn;
        out[((size_t)b * DIM + i) * 2 + 1] = a.y * invn;
    }
}

extern "C" void kernel_launch(void* const* d_in, const int* in_sizes, int n_in,
                              void* d_out, int out_size, void* d_ws, size_t ws_size,
                              hipStream_t stream) {
    const float* base = (const float*)d_in[0];   // (64, 2048) f32
    const float* upar = (const float*)d_in[1];   // (64, 8, 88) f32
    const float* lcu  = (const float*)d_in[2];   // (64, 8) f32
    const float* pc   = (const float*)d_in[3];   // (4,) f32
    float* out = (float*)d_out;                  // (64, 2048, 2) f32

    const size_t plane = (size_t)BSZ * DIM * sizeof(float2);   // 1 MB
    char* ws = (char*)d_ws;
    float2* working = (float2*)ws;
    float2* acc     = (float2*)(ws + plane);
    float2* pA      = (float2*)(ws + 2 * plane);
    float2* pB      = (float2*)(ws + 2 * plane + (size_t)NT * plane);
    float2* pC      = (float2*)(ws + 2 * plane + (size_t)2 * NT * plane);

    setup_kernel<<<BSZ, 256, 0, stream>>>(base, pc, working, acc);

    if (ws_size >= (2 + 3 * (size_t)NT) * plane) {
        // fused path: 5 launches, no separate reduce
        evolve_kernel<false><<<BSZ * NT, 256, 0, stream>>>(working, upar, lcu, pA, pc, acc, 0, 1);
        evolve_kernel<true ><<<BSZ * NT, 256, 0, stream>>>(pA,      upar, lcu, pB, pc, acc, 1, 1);
        evolve_kernel<true ><<<BSZ * NT, 256, 0, stream>>>(pB,      upar, lcu, pC, pc, acc, 2, 1);
        final_kernel<<<BSZ * 8, 256, 0, stream>>>(pC, pc, acc, out);
    } else {
        // fallback: partial ping through pA only, explicit reduce
        int tpb = 1;
        while (tpb < NT && 2 * plane + (size_t)(NT / tpb) * plane > ws_size) tpb <<= 1;
        int nchunks = NT / tpb;
        for (int k = 1; k <= NPC - 1; ++k) {
            evolve_kernel<false><<<BSZ * nchunks, 256, 0, stream>>>(working, upar, lcu, pA, pc, acc, 0, tpb);
            reduce_kernel<<<BSZ * 8, 256, 0, stream>>>(pA, pc, working, acc, out,
                                                       nchunks, k, (k == NPC - 1) ? 1 : 0);
        }
    }
}

// Round 5
// 87.167 us; speedup vs baseline: 2.6748x; 1.1588x over previous
//
#include <hip/hip_runtime.h>
#include <utility>

#define DIM 2048
#define NQ 11
#define NROT 88
#define BSZ 64
#define NT 8
#define NPC 4   // DEGREE+1

// ---------------------------------------------------------------------------
// Compile-time gate schedule. Gate G in [0,88); wire w <-> state bit 10-w.
// ---------------------------------------------------------------------------
constexpr int g_type(int G) {
    int j = G % 44;
    return (j < 11 || (j >= 22 && j < 33)) ? 0 : 1;   // 0=RY, 1=CRX
}
constexpr int g_pt(int G) {
    int j = G % 44;
    if (j < 11) return 10 - j;
    if (j < 22) { int i = 21 - j; int tw = (i + 1 == NQ) ? 0 : i + 1; return 10 - tw; }
    if (j < 33) return 10 - (j - 22);
    if (j == 33) return 1;
    int i = j - 34; int tw = (i + 10) % NQ; return 10 - tw;
}
constexpr int g_pcb(int G) {
    int j = G % 44;
    if (j >= 11 && j < 22) { int i = 21 - j; return 10 - i; }
    if (j == 33) return 0;
    if (j >= 34) { int i = j - 34; return 10 - i; }
    return -1;  // RY
}
constexpr int block_parity(int G) {          // parity of #block-bit (pt>=8) gates before G
    int c = 0;
    for (int g = 0; g < G; ++g) if (g_pt(g) >= 8) c ^= 1;
    return c;
}

// ---------------------------------------------------------------------------
// Lane exchange across tid bit LB (state bit LB+2).
// ---------------------------------------------------------------------------
template<int LB>
__device__ __forceinline__ float lx(float x) {
    if constexpr (LB == 0) {
        return __int_as_float(__builtin_amdgcn_update_dpp(
            __float_as_int(x), __float_as_int(x), 0xB1, 0xF, 0xF, true)); // quad_perm xor1
    } else if constexpr (LB == 1) {
        return __int_as_float(__builtin_amdgcn_update_dpp(
            __float_as_int(x), __float_as_int(x), 0x4E, 0xF, 0xF, true)); // quad_perm xor2
    } else if constexpr (LB == 2) {
        return __int_as_float(__builtin_amdgcn_ds_swizzle(__float_as_int(x), 0x101F)); // xor4
    } else if constexpr (LB == 3) {
        return __int_as_float(__builtin_amdgcn_ds_swizzle(__float_as_int(x), 0x201F)); // xor8
    } else if constexpr (LB == 4) {
        return __int_as_float(__builtin_amdgcn_ds_swizzle(__float_as_int(x), 0x401F)); // xor16
    } else {
        return __shfl_xor(x, 32, 64);                                                  // xor32
    }
}

// ---------------------------------------------------------------------------
// Layout: 512 threads, thread tid holds amps a = tid*4 + (2m+e), m,e in {0,1}.
//   R[m] = (re(e=0), re(e=1)), I[m] likewise.
//   amp bits: 0=e, 1=m, 2..7=lane(tid 0..5), 8..10=block(tid 6..8)
// ---------------------------------------------------------------------------
template<int G>
__device__ __forceinline__ void apply_gate(
    float2 (&R)[2], float2 (&I)[2],
    const float* __restrict__ sc, const float* __restrict__ ss,
    float4* __restrict__ exbuf, const int tid)
{
    constexpr int type = g_type(G);
    constexpr int pt   = g_pt(G);
    constexpr int pcb  = g_pcb(G);
    const float c = sc[G];
    const float s = ss[G];

    if constexpr (pt == 0) {
        // -------- component (e) pair --------
        if constexpr (type == 0) {
#pragma unroll
            for (int m = 0; m < 2; ++m) {
                float er = R[m].x, orr = R[m].y, ei = I[m].x, oi = I[m].y;
                R[m].x = c*er - s*orr;  R[m].y = s*er + c*orr;
                I[m].x = c*ei - s*oi;   I[m].y = s*ei + c*oi;
            }
        } else if constexpr (pcb == 1) {
            float er = R[1].x, orr = R[1].y, ei = I[1].x, oi = I[1].y;
            R[1].x = c*er + s*oi;   I[1].x = c*ei - s*orr;
            R[1].y = c*orr + s*ei;  I[1].y = c*oi - s*er;
        } else {
            const bool ctrl = (tid >> (pcb - 2)) & 1;
            if (ctrl) {
#pragma unroll
                for (int m = 0; m < 2; ++m) {
                    float er = R[m].x, orr = R[m].y, ei = I[m].x, oi = I[m].y;
                    R[m].x = c*er + s*oi;   I[m].x = c*ei - s*orr;
                    R[m].y = c*orr + s*ei;  I[m].y = c*oi - s*er;
                }
            }
        }
    } else if constexpr (pt == 1) {
        // -------- slot (m) pair --------
        if constexpr (type == 0) {
            float2 l = R[0], h = R[1], li = I[0], hi = I[1];
            R[0].x = c*l.x - s*h.x;   R[0].y = c*l.y - s*h.y;
            R[1].x = s*l.x + c*h.x;   R[1].y = s*l.y + c*h.y;
            I[0].x = c*li.x - s*hi.x; I[0].y = c*li.y - s*hi.y;
            I[1].x = s*li.x + c*hi.x; I[1].y = s*li.y + c*hi.y;
        } else if constexpr (pcb == 0) {
            float lr = R[0].y, li = I[0].y, hr = R[1].y, hi = I[1].y;
            R[0].y = c*lr + s*hi;   I[0].y = c*li - s*hr;
            R[1].y = c*hr + s*li;   I[1].y = c*hi - s*lr;
        } else {
            const bool ctrl = (tid >> (pcb - 2)) & 1;
            if (ctrl) {
                float2 l = R[0], h = R[1], li = I[0], hi = I[1];
                R[0].x = c*l.x + s*hi.x;  R[0].y = c*l.y + s*hi.y;
                I[0].x = c*li.x - s*h.x;  I[0].y = c*li.y - s*h.y;
                R[1].x = c*h.x + s*li.x;  R[1].y = c*h.y + s*li.y;
                I[1].x = c*hi.x - s*l.x;  I[1].y = c*hi.y - s*l.y;
            }
        }
    } else if constexpr (pt <= 7) {
        // -------- lane exchange --------
        constexpr int lb = pt - 2;
        if constexpr (type == 0) {
            const float sg = ((tid >> lb) & 1) ? s : -s;
#pragma unroll
            for (int m = 0; m < 2; ++m) {
                float prx = lx<lb>(R[m].x), pry = lx<lb>(R[m].y);
                float pix = lx<lb>(I[m].x), piy = lx<lb>(I[m].y);
                R[m].x = c*R[m].x + sg*prx;  R[m].y = c*R[m].y + sg*pry;
                I[m].x = c*I[m].x + sg*pix;  I[m].y = c*I[m].y + sg*piy;
            }
        } else if constexpr (pcb == 0) {
#pragma unroll
            for (int m = 0; m < 2; ++m) {
                float pry = lx<lb>(R[m].y), piy = lx<lb>(I[m].y);
                R[m].y = c*R[m].y + s*piy;
                I[m].y = c*I[m].y - s*pry;
            }
        } else if constexpr (pcb == 1) {
            float prx = lx<lb>(R[1].x), pry = lx<lb>(R[1].y);
            float pix = lx<lb>(I[1].x), piy = lx<lb>(I[1].y);
            R[1].x = c*R[1].x + s*pix;  R[1].y = c*R[1].y + s*piy;
            I[1].x = c*I[1].x - s*prx;  I[1].y = c*I[1].y - s*pry;
        } else {
            const bool ctrl = (tid >> (pcb - 2)) & 1;
            if (ctrl) {
#pragma unroll
                for (int m = 0; m < 2; ++m) {
                    float prx = lx<lb>(R[m].x), pry = lx<lb>(R[m].y);
                    float pix = lx<lb>(I[m].x), piy = lx<lb>(I[m].y);
                    R[m].x = c*R[m].x + s*pix;  R[m].y = c*R[m].y + s*piy;
                    I[m].x = c*I[m].x - s*prx;  I[m].y = c*I[m].y - s*pry;
                }
            }
        }
    } else {
        // -------- block-bit exchange via LDS (dbuf, 1 barrier) --------
        constexpr int par = block_parity(G);
        float4* buf = exbuf + par * 1024;
        const int ptid = tid ^ (1 << (pt - 2));   // ^64 / ^128 / ^256
        if constexpr (type == 0) {
#pragma unroll
            for (int m = 0; m < 2; ++m)
                buf[m * 512 + tid] = make_float4(R[m].x, R[m].y, I[m].x, I[m].y);
            __syncthreads();
            const float sg = ((tid >> (pt - 2)) & 1) ? s : -s;
#pragma unroll
            for (int m = 0; m < 2; ++m) {
                float4 v = buf[m * 512 + ptid];
                R[m].x = c*R[m].x + sg*v.x;  R[m].y = c*R[m].y + sg*v.y;
                I[m].x = c*I[m].x + sg*v.z;  I[m].y = c*I[m].y + sg*v.w;
            }
        } else if constexpr (pcb == 0) {
            float2* f2 = (float2*)buf;
#pragma unroll
            for (int m = 0; m < 2; ++m)
                f2[m * 512 + tid] = make_float2(R[m].y, I[m].y);
            __syncthreads();
#pragma unroll
            for (int m = 0; m < 2; ++m) {
                float2 v = f2[m * 512 + ptid];
                R[m].y = c*R[m].y + s*v.y;
                I[m].y = c*I[m].y - s*v.x;
            }
        } else if constexpr (pcb == 1) {
            buf[tid] = make_float4(R[1].x, R[1].y, I[1].x, I[1].y);
            __syncthreads();
            float4 v = buf[ptid];
            R[1].x = c*R[1].x + s*v.z;  R[1].y = c*R[1].y + s*v.w;
            I[1].x = c*I[1].x - s*v.x;  I[1].y = c*I[1].y - s*v.y;
        } else {
            const bool ctrl = (tid >> (pcb - 2)) & 1;
            if (ctrl) {
#pragma unroll
                for (int m = 0; m < 2; ++m)
                    buf[m * 512 + tid] = make_float4(R[m].x, R[m].y, I[m].x, I[m].y);
            }
            __syncthreads();
            if (ctrl) {
#pragma unroll
                for (int m = 0; m < 2; ++m) {
                    float4 v = buf[m * 512 + ptid];
                    R[m].x = c*R[m].x + s*v.z;  R[m].y = c*R[m].y + s*v.w;
                    I[m].x = c*I[m].x - s*v.x;  I[m].y = c*I[m].y - s*v.y;
                }
            }
        }
        // no trailing barrier: parity buffer reused 2 block-gates later; the
        // intervening block gate's barrier orders those reads before writes.
    }
}

template<int... Gs>
__device__ __forceinline__ void apply_all(std::integer_sequence<int, Gs...>,
    float2 (&R)[2], float2 (&I)[2],
    const float* __restrict__ sc, const float* __restrict__ ss,
    float4* __restrict__ exbuf, const int tid)
{
    (apply_gate<Gs>(R, I, sc, ss, exbuf, tid), ...);
}

// ---------------------------------------------------------------------------
// Evolve. MODE 0: src = base (f32 real), normalize inline, t==0 writes
// acc = pc0*base. MODE 1: src = prev partials, inline-reduce; t==0 folds
// pc[kprev]*working into acc. MODE 2: src = working (fallback path).
// One (b,t) per block, 512 threads, 4 amps/thread.
// ---------------------------------------------------------------------------
template<int MODE>
__global__ __launch_bounds__(512) void evolve_kernel(
    const void* __restrict__ src, const float* __restrict__ uparams,
    const float* __restrict__ lcu, float2* __restrict__ pout,
    const float* __restrict__ pcoef, float2* __restrict__ acc, int kprev)
{
    __shared__ float4 exbuf[2048];          // 2 x 512 x 2 float4 (dbuf) = 32 KB
    __shared__ float sc[NROT], ss[NROT];
    __shared__ float red[9];

    const int b = blockIdx.x >> 3;
    const int t = blockIdx.x & 7;
    const int tid = threadIdx.x;

    float2 R[2], I[2];
    if constexpr (MODE == 0) {
        const float4* b4 = (const float4*)((const float*)src + (size_t)b * DIM);
        float4 v = b4[tid];
        float loc = v.x*v.x + v.y*v.y + v.z*v.z + v.w*v.w;
        for (int off = 32; off > 0; off >>= 1) loc += __shfl_down(loc, off, 64);
        if ((tid & 63) == 0) red[tid >> 6] = loc;
        __syncthreads();
        if (tid == 0) { float sm = 0.f; for (int w = 0; w < 8; ++w) sm += red[w]; red[8] = sm; }
        __syncthreads();
        const float inv = rsqrtf(red[8]);
        R[0] = make_float2(v.x * inv, v.y * inv);
        R[1] = make_float2(v.z * inv, v.w * inv);
        I[0] = make_float2(0.f, 0.f);
        I[1] = make_float2(0.f, 0.f);
        if (t == 0) {
            const float p0 = pcoef[0];
            float4* a4 = (float4*)(acc + (size_t)b * DIM);
            a4[tid*2+0] = make_float4(p0*R[0].x, 0.f, p0*R[0].y, 0.f);
            a4[tid*2+1] = make_float4(p0*R[1].x, 0.f, p0*R[1].y, 0.f);
        }
    } else if constexpr (MODE == 1) {
        R[0] = R[1] = I[0] = I[1] = make_float2(0.f, 0.f);
        const float2* s2 = (const float2*)src;
        for (int cc = 0; cc < NT; ++cc) {
            const float4* p4 = (const float4*)(s2 + ((size_t)b * NT + cc) * DIM);
#pragma unroll
            for (int m = 0; m < 2; ++m) {
                float4 v = p4[tid*2+m];
                R[m].x += v.x; I[m].x += v.y; R[m].y += v.z; I[m].y += v.w;
            }
        }
        if (t == 0) {
            const float pk = pcoef[kprev];
            float4* a4 = (float4*)(acc + (size_t)b * DIM);
#pragma unroll
            for (int m = 0; m < 2; ++m) {
                float4 v = a4[tid*2+m];
                v.x += pk * R[m].x; v.y += pk * I[m].x;
                v.z += pk * R[m].y; v.w += pk * I[m].y;
                a4[tid*2+m] = v;
            }
        }
    } else {
        const float2* s2 = (const float2*)src;
        const float4* p4 = (const float4*)(s2 + (size_t)b * DIM);
#pragma unroll
        for (int m = 0; m < 2; ++m) {
            float4 v = p4[tid*2+m];
            R[m].x = v.x; I[m].x = v.y; R[m].y = v.z; I[m].y = v.w;
        }
    }

    if (tid < NROT) {
        float th = 0.5f * uparams[(b * NT + t) * NROT + tid];
        sc[tid] = cosf(th); ss[tid] = sinf(th);
    }
    __syncthreads();

    apply_all(std::make_integer_sequence<int, NROT>{}, R, I, sc, ss, exbuf, tid);

    const float coeff = lcu[b * NT + t];
    float4* o4 = (float4*)(pout + ((size_t)b * NT + t) * DIM);
#pragma unroll
    for (int m = 0; m < 2; ++m)
        o4[tid*2+m] = make_float4(coeff*R[m].x, coeff*I[m].x, coeff*R[m].y, coeff*I[m].y);
}

// ---------------------------------------------------------------------------
// Final: out = (acc + pc[NPC-1] * rowsum(partial_last)) / sum|pc|
// ---------------------------------------------------------------------------
__global__ __launch_bounds__(256) void final_kernel(
    const float2* __restrict__ partial, const float* __restrict__ pcoef,
    const float2* __restrict__ acc, float* __restrict__ out)
{
    int b = blockIdx.x >> 3;
    int i = ((blockIdx.x & 7) << 8) | threadIdx.x;
    float sr = 0.f, si = 0.f;
    for (int c = 0; c < NT; ++c) {
        float2 v = partial[((size_t)b * NT + c) * DIM + i];
        sr += v.x; si += v.y;
    }
    float sabs = 0.f;
    for (int q = 0; q < NPC; ++q) sabs += fabsf(pcoef[q]);
    float invn = 1.0f / sabs;
    float pk = pcoef[NPC - 1];
    float2 a = acc[(size_t)b * DIM + i];
    out[((size_t)b * DIM + i) * 2 + 0] = (a.x + pk * sr) * invn;
    out[((size_t)b * DIM + i) * 2 + 1] = (a.y + pk * si) * invn;
}

// ---------------------------------------------------------------------------
// Fallback path helpers (small ws): setup + explicit reduce
// ---------------------------------------------------------------------------
__global__ __launch_bounds__(256) void setup_kernel(
    const float* __restrict__ base, const float* __restrict__ pc,
    float2* __restrict__ working, float2* __restrict__ acc)
{
    int b = blockIdx.x;
    int tid = threadIdx.x;
    __shared__ float red[4];
    float ssum = 0.f;
    for (int i = tid; i < DIM; i += 256) {
        float v = base[b * DIM + i];
        ssum += v * v;
    }
    for (int off = 32; off > 0; off >>= 1) ssum += __shfl_down(ssum, off, 64);
    if ((tid & 63) == 0) red[tid >> 6] = ssum;
    __syncthreads();
    if (tid == 0) red[0] = red[0] + red[1] + red[2] + red[3];
    __syncthreads();
    float inv = rsqrtf(red[0]);
    float p0 = pc[0];
    for (int i = tid; i < DIM; i += 256) {
        float v = base[b * DIM + i] * inv;
        working[b * DIM + i] = make_float2(v, 0.f);
        acc[b * DIM + i] = make_float2(p0 * v, 0.f);
    }
}

__global__ __launch_bounds__(256) void reduce_kernel(
    const float2* __restrict__ partial, const float* __restrict__ pcoef,
    float2* __restrict__ working, float2* __restrict__ acc,
    float* __restrict__ out, int k, int last)
{
    int b = blockIdx.x >> 3;
    int i = ((blockIdx.x & 7) << 8) | threadIdx.x;
    float pk = pcoef[k];
    float sr = 0.f, si = 0.f;
    for (int c = 0; c < NT; ++c) {
        float2 v = partial[((size_t)b * NT + c) * DIM + i];
        sr += v.x; si += v.y;
    }
    working[b * DIM + i] = make_float2(sr, si);
    float2 a = acc[b * DIM + i];
    a.x += pk * sr; a.y += pk * si;
    acc[b * DIM + i] = a;
    if (last) {
        float sabs = 0.f;
        for (int q = 0; q < NPC; ++q) sabs += fabsf(pcoef[q]);
        float invn = 1.0f / sabs;
        out[((size_t)b * DIM + i) * 2 + 0] = a.x * invn;
        out[((size_t)b * DIM + i) * 2 + 1] = a.y * invn;
    }
}

extern "C" void kernel_launch(void* const* d_in, const int* in_sizes, int n_in,
                              void* d_out, int out_size, void* d_ws, size_t ws_size,
                              hipStream_t stream) {
    const float* base = (const float*)d_in[0];   // (64, 2048) f32
    const float* upar = (const float*)d_in[1];   // (64, 8, 88) f32
    const float* lcu  = (const float*)d_in[2];   // (64, 8) f32
    const float* pc   = (const float*)d_in[3];   // (4,) f32
    float* out = (float*)d_out;                  // (64, 2048, 2) f32

    const size_t plane = (size_t)BSZ * DIM * sizeof(float2);   // 1 MB
    char* ws = (char*)d_ws;

    if (ws_size >= (1 + 3 * (size_t)NT) * plane) {
        // fused: 4 launches
        float2* acc = (float2*)ws;
        float2* pA  = (float2*)(ws + plane);
        float2* pB  = (float2*)(ws + plane + (size_t)NT * plane);
        float2* pC  = (float2*)(ws + plane + (size_t)2 * NT * plane);
        evolve_kernel<0><<<BSZ * NT, 512, 0, stream>>>(base, upar, lcu, pA, pc, acc, 0);
        evolve_kernel<1><<<BSZ * NT, 512, 0, stream>>>(pA,   upar, lcu, pB, pc, acc, 1);
        evolve_kernel<1><<<BSZ * NT, 512, 0, stream>>>(pB,   upar, lcu, pC, pc, acc, 2);
        final_kernel<<<BSZ * 8, 256, 0, stream>>>(pC, pc, acc, out);
    } else {
        // fallback: working + acc + one partial buffer (10 MB)
        float2* working = (float2*)ws;
        float2* acc     = (float2*)(ws + plane);
        float2* pA      = (float2*)(ws + 2 * plane);
        setup_kernel<<<BSZ, 256, 0, stream>>>(base, pc, working, acc);
        for (int k = 1; k <= NPC - 1; ++k) {
            evolve_kernel<2><<<BSZ * NT, 512, 0, stream>>>(working, upar, lcu, pA, pc, acc, 0);
            reduce_kernel<<<BSZ * 8, 256, 0, stream>>>(pA, pc, working, acc, out,
                                                       k, (k == NPC - 1) ? 1 : 0);
        }
    }
}